// Round 7
// baseline (460.361 us; speedup 1.0000x reference)
//
#include <hip/hip_runtime.h>
#include <math.h>
#include <stdint.h>

// B=8, N=M=4096, C=256, H=W=64, KS=5 (fixed by reference).
#define EPSF 1e-6f

typedef _Float16 half_t;
typedef _Float16 half8 __attribute__((ext_vector_type(8)));
typedef _Float16 half4 __attribute__((ext_vector_type(4)));
typedef float f32x4 __attribute__((ext_vector_type(4)));

#define MFMA16(A, B, C) __builtin_amdgcn_mfma_f32_16x16x32_f16(A, B, C, 0, 0, 0)

#define SBAR() __builtin_amdgcn_s_barrier()
#define WAIT_LGKM0()                                        \
  do {                                                      \
    asm volatile("s_waitcnt lgkmcnt(0)" ::: "memory");      \
    __builtin_amdgcn_sched_barrier(0);                      \
  } while (0)
#define WAIT_VM0_LGKM0()                                            \
  do {                                                              \
    asm volatile("s_waitcnt vmcnt(0) lgkmcnt(0)" ::: "memory");     \
    __builtin_amdgcn_sched_barrier(0);                              \
  } while (0)

__device__ __forceinline__ float softplusf(float x) {
  return (x > 20.f) ? x : log1pf(expf(x));
}

__device__ __forceinline__ void split4(const float4 v, half4& h, half4& l) {
  h.x = (half_t)v.x; l.x = (half_t)(v.x - (float)h.x);
  h.y = (half_t)v.y; l.y = (half_t)(v.y - (float)h.y);
  h.z = (half_t)v.z; l.z = (half_t)(v.z - (float)h.z);
  h.w = (half_t)v.w; l.w = (half_t)(v.w - (float)h.w);
}

// --------------------------------------------------------------------------
// Shared MFMA machinery: 128x128 tile, BK=32, 256 threads (4 waves 2x2),
// wave tile 64x64 = 4x4 frags of 16x16x32 f16 MFMA, 3-term hi/lo split.
// SINGLE 32 KB LDS buffer (4 planes x 8 KB) -> 4 blocks/CU: cross-block
// wave overlap (m114) hides the stage/drain phases (m97 structure).
// --------------------------------------------------------------------------

__device__ __forceinline__ void stage_gld(const half_t* __restrict__ src, size_t rowbase,
                                          int ld, int k0, half_t* __restrict__ dst, int tid) {
#pragma unroll
  for (int r = 0; r < 2; ++r) {
    const int f = tid + r * 256;          // 128 rows x 4 chunks of 8 halfs
    const half_t* g = src + (rowbase + (size_t)(f >> 2)) * (size_t)ld + k0 + (f & 3) * 8;
    const __attribute__((address_space(1))) unsigned int* gp =
        (const __attribute__((address_space(1))) unsigned int*)(uintptr_t)g;
    __attribute__((address_space(3))) unsigned int* lp =
        (__attribute__((address_space(3))) unsigned int*)(uintptr_t)(dst + f * 8);
    __builtin_amdgcn_global_load_lds(gp, lp, 16, 0, 0);
  }
}

__device__ __forceinline__ void frag_compute(const half_t* __restrict__ As_h,
                                             const half_t* __restrict__ As_l,
                                             const half_t* __restrict__ Bs_h,
                                             const half_t* __restrict__ Bs_l,
                                             f32x4 (&acc)[4][4], int lane, int wm, int wn) {
  const int lr = lane & 15, lg = lane >> 4;
  half8 ah[4], al[4], bh[4], bl[4];
#pragma unroll
  for (int i = 0; i < 4; ++i) {
    const int ar = (wm * 64 + i * 16 + lr) * 32 + lg * 8;
    ah[i] = *(const half8*)&As_h[ar];
    al[i] = *(const half8*)&As_l[ar];
    const int br = (wn * 64 + i * 16 + lr) * 32 + lg * 8;
    bh[i] = *(const half8*)&Bs_h[br];
    bl[i] = *(const half8*)&Bs_l[br];
  }
#pragma unroll
  for (int i = 0; i < 4; ++i)
#pragma unroll
    for (int j = 0; j < 4; ++j) {
      acc[i][j] = MFMA16(ah[i], bh[j], acc[i][j]);
      acc[i][j] = MFMA16(ah[i], bl[j], acc[i][j]);
      acc[i][j] = MFMA16(al[i], bh[j], acc[i][j]);
    }
}

// --------------------------------------------------------------------------
// 0) init: scs[c] = 1/softplus(scale[c]); zero ksm (proj atomicAdds into it).
// --------------------------------------------------------------------------
__global__ void init_k(const float* __restrict__ scale, float* __restrict__ scs,
                       float* __restrict__ ksm) {
  const int i = blockIdx.x * 256 + threadIdx.x;
  if (i < 2048) ksm[i] = 0.f;
  if (i < 256) scs[i] = 1.f / softplusf(scale[i]);
}

// --------------------------------------------------------------------------
// 1) Projections: single-buffer 32 KB, 2 barriers/step; t+1 reg loads issued
//    before compute(t) so they hide under the MFMA phase.
//    which==0 (q): A=Wq, B=query -> coalesced half4 stores along d.
//    which==1/2 (k/v): transposed [b][c][m] out via chunked LDS restage.
//    which==1 additionally atomicAdds ksum partials into ksm.
// --------------------------------------------------------------------------
__global__ __launch_bounds__(256, 4) void proj_mfma(
    const float* __restrict__ query, const float* __restrict__ key,
    const float* __restrict__ value,
    const float* __restrict__ Wq, const float* __restrict__ Wk, const float* __restrict__ Wv,
    const float* __restrict__ rsc,
    half_t* __restrict__ qh, half_t* __restrict__ ql,
    half_t* __restrict__ khT, half_t* __restrict__ klT,
    half_t* __restrict__ vhT, half_t* __restrict__ vlT,
    float* __restrict__ ksm) {
  const int which = blockIdx.z;
  const int tid = threadIdx.x;
  const int lane = tid & 63, wave = tid >> 6, wm = wave >> 1, wn = wave & 1;
  const int lr = lane & 15, lg = lane >> 4;

  const float* srcA;
  const float* srcB;
  int rA0, rB0;
  if (which == 0) {
    srcA = Wq;    rA0 = blockIdx.y * 128;  srcB = query; rB0 = blockIdx.x * 128;
  } else if (which == 1) {
    srcA = key;   rA0 = blockIdx.x * 128;  srcB = Wk;    rB0 = blockIdx.y * 128;
  } else {
    srcA = value; rA0 = blockIdx.x * 128;  srcB = Wv;    rB0 = blockIdx.y * 128;
  }

  __shared__ __align__(16) half_t sm[16384];  // {Ah,Al,Bh,Bl} x 4096 halfs
  f32x4 acc[4][4] = {};
  float4 RA[4], RB[4];

  auto load_tile = [&](int ks) {
    const int k0 = ks * 32;
#pragma unroll
    for (int r = 0; r < 4; ++r) {
      const int f = tid + r * 256;
      const int row = f >> 3, c4 = f & 7;
      RA[r] = *(const float4*)&srcA[(size_t)(rA0 + row) * 256 + k0 + c4 * 4];
      RB[r] = *(const float4*)&srcB[(size_t)(rB0 + row) * 256 + k0 + c4 * 4];
    }
  };
  auto split_write = [&]() {
#pragma unroll
    for (int r = 0; r < 4; ++r) {
      const int f = tid + r * 256;
      const int row = f >> 3, c4 = f & 7;
      half4 h, l;
      split4(RA[r], h, l);
      *(half4*)&sm[row * 32 + c4 * 4] = h;
      *(half4*)&sm[4096 + row * 32 + c4 * 4] = l;
      split4(RB[r], h, l);
      *(half4*)&sm[8192 + row * 32 + c4 * 4] = h;
      *(half4*)&sm[12288 + row * 32 + c4 * 4] = l;
    }
  };

  load_tile(0);
  split_write();
  WAIT_LGKM0();
  SBAR();
#pragma unroll
  for (int t = 0; t < 8; ++t) {
    if (t + 1 < 8) load_tile(t + 1);  // async reg loads, consumed after next bar
    frag_compute(sm, sm + 4096, sm + 8192, sm + 12288, acc, lane, wm, wn);
    SBAR();  // all waves done reading sm
    if (t + 1 < 8) {
      split_write();
      WAIT_LGKM0();
    }
    SBAR();  // writes visible
  }

  if (which == 0) {
    // D: row = d_local (A=Wq side), col = n_local. Store along d (contiguous).
    const int dbase = rA0 + wm * 64;
    float rs[4][4];
#pragma unroll
    for (int i = 0; i < 4; ++i)
#pragma unroll
      for (int r = 0; r < 4; ++r) rs[i][r] = rsc[dbase + i * 16 + lg * 4 + r];
#pragma unroll
    for (int j = 0; j < 4; ++j) {
      const size_t nflat = (size_t)rB0 + wn * 64 + j * 16 + lr;
#pragma unroll
      for (int i = 0; i < 4; ++i) {
        half4 hv, lv;
#pragma unroll
        for (int r = 0; r < 4; ++r) {
          float v = acc[i][j][r];
          v = (fmaxf(v, 0.f) + EPSF) * rs[i][r];
          v = v * v * v;  // q**3/||q||*||q|| == q**3
          const half_t h = (half_t)v;
          hv[r] = h;
          lv[r] = (half_t)(v - (float)h);
        }
        const size_t o = nflat * 256 + dbase + i * 16 + lg * 4;
        *(half4*)&qh[o] = hv;
        *(half4*)&ql[o] = lv;
      }
    }
  } else {
    // D: row = m_local, col = c_local. Restage [32 c][128 m] chunks in LDS,
    // then coalesced half8 stores. which==1: accumulate ksum partials too.
    const int b = rA0 >> 12, m0 = rA0 & 4095;
    half_t* Thg = (which == 1) ? khT : vhT;
    half_t* Tlg = (which == 1) ? klT : vlT;
    const bool act = (which == 1);
    half_t* Tt = sm;            // [32][136]
    half_t* Tl2 = sm + 4352;    // [32][136]
    float kj[4] = {0.f, 0.f, 0.f, 0.f};
#pragma unroll
    for (int g = 0; g < 4; ++g) {
      if (wn == (g >> 1)) {
#pragma unroll
        for (int jj = 0; jj < 2; ++jj) {
          const int j = (g & 1) * 2 + jj;
          const int c = rB0 + wn * 64 + j * 16 + lr;
          const float rv = act ? rsc[c] : 1.f;
          const int crel = jj * 16 + lr;
#pragma unroll
          for (int i = 0; i < 4; ++i) {
            const int ml = wm * 64 + i * 16 + lg * 4;
            half4 hv, lv;
#pragma unroll
            for (int r = 0; r < 4; ++r) {
              float v = acc[i][j][r];
              if (act) { v = (fmaxf(v, 0.f) + EPSF) * rv; v = v * v * v; kj[j] += v; }
              const half_t h = (half_t)v;
              hv[r] = h;
              lv[r] = (half_t)(v - (float)h);
            }
            *(half4*)&Tt[crel * 136 + ml] = hv;
            *(half4*)&Tl2[crel * 136 + ml] = lv;
          }
        }
      }
      __syncthreads();
      {
        const int cr = tid >> 3, mm = (tid & 7) * 16;
        const size_t ga = ((size_t)(b * 256 + rB0 + g * 32 + cr)) * 4096 + m0 + mm;
        *(half8*)&Thg[ga]     = *(const half8*)&Tt[cr * 136 + mm];
        *(half8*)&Thg[ga + 8] = *(const half8*)&Tt[cr * 136 + mm + 8];
        *(half8*)&Tlg[ga]     = *(const half8*)&Tl2[cr * 136 + mm];
        *(half8*)&Tlg[ga + 8] = *(const half8*)&Tl2[cr * 136 + mm + 8];
      }
      __syncthreads();
    }
    if (act) {
#pragma unroll
      for (int j = 0; j < 4; ++j) {
        float s = kj[j];
        s += __shfl_xor(s, 16, 64);
        s += __shfl_xor(s, 32, 64);
        if (lg == 0) atomicAdd(&ksm[b * 256 + rB0 + wn * 64 + j * 16 + lr], s);
      }
    }
  }
}

// --------------------------------------------------------------------------
// 3) kv partials: kvT[d][c] = sum_m v[m][d]*k3[m][c]. Single-buffer m97
//    schedule: stage -> drain -> bar -> compute -> bar. 32 KB LDS.
// --------------------------------------------------------------------------
__global__ __launch_bounds__(256) void kv_mfma(
    const half_t* __restrict__ vhT, const half_t* __restrict__ vlT,
    const half_t* __restrict__ khT, const half_t* __restrict__ klT,
    float* __restrict__ kvp) {
  const int b = blockIdx.z >> 3, s = blockIdx.z & 7;
  const int d0 = blockIdx.x * 128, c0 = blockIdx.y * 128;
  const int tid = threadIdx.x;
  __shared__ __align__(16) half_t sm[16384];
  f32x4 acc[4][4] = {};
  const int lane = tid & 63, wave = tid >> 6, wm = wave >> 1, wn = wave & 1;
  const int lr = lane & 15, lg = lane >> 4;
  const size_t arow = (size_t)b * 256 + d0, brow = (size_t)b * 256 + c0;

#pragma unroll
  for (int t = 0; t < 16; ++t) {
    const int k0 = s * 512 + t * 32;
    stage_gld(vhT, arow, 4096, k0, sm, tid);
    stage_gld(vlT, arow, 4096, k0, sm + 4096, tid);
    stage_gld(khT, brow, 4096, k0, sm + 8192, tid);
    stage_gld(klT, brow, 4096, k0, sm + 12288, tid);
    WAIT_VM0_LGKM0();
    SBAR();
    frag_compute(sm, sm + 4096, sm + 8192, sm + 12288, acc, lane, wm, wn);
    SBAR();
  }

  float* outp = kvp + ((size_t)(b * 8 + s)) * 65536;
#pragma unroll
  for (int j = 0; j < 4; ++j) {
    const int c = c0 + wn * 64 + j * 16 + lr;
#pragma unroll
    for (int i = 0; i < 4; ++i) {
      const int d = d0 + wm * 64 + i * 16 + lg * 4;
#pragma unroll
      for (int r = 0; r < 4; ++r) outp[(size_t)(d + r) * 256 + c] = acc[i][j][r];
    }
  }
}

__global__ __launch_bounds__(256) void kv_red(const float* __restrict__ kvp,
                                              half_t* __restrict__ kvTh,
                                              half_t* __restrict__ kvTl) {
  const size_t idx = (size_t)blockIdx.x * 256 + threadIdx.x;  // 524288
  const int b = (int)(idx >> 16);
  const int dc = (int)(idx & 65535);
  float s = 0.f;
#pragma unroll
  for (int t = 0; t < 8; ++t) s += kvp[((size_t)(b * 8 + t)) * 65536 + dc];
  const half_t h = (half_t)s;
  kvTh[idx] = h;
  kvTl[idx] = (half_t)(s - (float)h);
}

// --------------------------------------------------------------------------
// 5) x1[n][d] = (q3[n,:].kvT[d,:]) * z[n], z fused in-kernel from staged q
//    planes. Single-buffer m97 schedule, 32 KB LDS. Out: xt[b][d][n] fp32.
// --------------------------------------------------------------------------
__global__ __launch_bounds__(256) void x1_mfma(
    const half_t* __restrict__ qh, const half_t* __restrict__ ql,
    const half_t* __restrict__ kvTh, const half_t* __restrict__ kvTl,
    const float* __restrict__ ksm, float* __restrict__ xt) {
  const int b = blockIdx.z, n0 = blockIdx.x * 128, d0t = blockIdx.y * 128;
  const int tid = threadIdx.x;
  __shared__ __align__(16) half_t sm[16384];
  __shared__ float zden[128];
  f32x4 acc[4][4] = {};
  const int lane = tid & 63, wave = tid >> 6, wm = wave >> 1, wn = wave & 1;
  const int lr = lane & 15, lg = lane >> 4;
  const size_t arow = (size_t)b * 4096 + n0, brow = (size_t)b * 256 + d0t;

  float zpart = 0.f;
  const int zrow = tid >> 1, zkh = tid & 1;
#pragma unroll
  for (int t = 0; t < 8; ++t) {
    const int k0 = t * 32;
    stage_gld(qh, arow, 256, k0, sm, tid);
    stage_gld(ql, arow, 256, k0, sm + 4096, tid);
    stage_gld(kvTh, brow, 256, k0, sm + 8192, tid);
    stage_gld(kvTl, brow, 256, k0, sm + 12288, tid);
    WAIT_VM0_LGKM0();
    SBAR();
    frag_compute(sm, sm + 4096, sm + 8192, sm + 12288, acc, lane, wm, wn);
    {  // z partial: q3 row dot ksum for this k-chunk (reads staged planes)
      const half_t* hp = sm + zrow * 32 + zkh * 16;
      const half_t* lp = sm + 4096 + zrow * 32 + zkh * 16;
      const half8 h0 = *(const half8*)&hp[0];
      const half8 h1 = *(const half8*)&hp[8];
      const half8 l0 = *(const half8*)&lp[0];
      const half8 l1 = *(const half8*)&lp[8];
      const float* ksp = ksm + b * 256 + t * 32 + zkh * 16;
#pragma unroll
      for (int u = 0; u < 8; ++u) {
        zpart += ((float)h0[u] + (float)l0[u]) * ksp[u];
        zpart += ((float)h1[u] + (float)l1[u]) * ksp[8 + u];
      }
    }
    SBAR();
  }

  zpart += __shfl_xor(zpart, 1, 64);
  if ((tid & 1) == 0) zden[zrow] = zpart;
  __syncthreads();

#pragma unroll
  for (int i = 0; i < 4; ++i) {
    const int nl = wm * 64 + i * 16 + lg * 4;  // local row in [0,128)
    float zr[4];
#pragma unroll
    for (int r = 0; r < 4; ++r) zr[r] = 1.f / (zden[nl + r] + EPSF);
#pragma unroll
    for (int j = 0; j < 4; ++j) {
      const int d = d0t + wn * 64 + j * 16 + lr;
      *(float4*)&xt[((size_t)b * 256 + d) * 4096 + n0 + nl] =
          make_float4(acc[i][j][0] * zr[0], acc[i][j][1] * zr[1],
                      acc[i][j][2] * zr[2], acc[i][j][3] * zr[3]);
    }
  }
}

// --------------------------------------------------------------------------
// 6) Depthwise 5x5 conv + bias on (B,C,64,64) planes (verified).
// --------------------------------------------------------------------------
__global__ __launch_bounds__(256) void dwconv_kernel(const float* __restrict__ xt,
                                                     const float* __restrict__ w,
                                                     const float* __restrict__ bias,
                                                     float* __restrict__ xc) {
  const int bc = blockIdx.x;  // b*256 + c
  const int c = bc & 255;
  const float* plane = xt + (size_t)bc * 4096;
  float* oplane = xc + (size_t)bc * 4096;

  __shared__ float Ls[68][72];
  const int tid = threadIdx.x;
  for (int i = tid; i < 68 * 72; i += 256) ((float*)Ls)[i] = 0.f;
  __syncthreads();
#pragma unroll
  for (int p = 0; p < 4; ++p) {
    const int f = tid + p * 256;
    const int y = f >> 4, x4 = f & 15;
    *(float4*)&Ls[2 + y][4 + x4 * 4] = *(const float4*)&plane[y * 64 + x4 * 4];
  }
  __syncthreads();

  float wreg[25];
#pragma unroll
  for (int t = 0; t < 25; ++t) wreg[t] = w[c * 25 + t];
  const float bv = bias[c];

  const int x = tid & 63, ys0 = (tid >> 6) * 16;
  float win[5][5];
#pragma unroll
  for (int r = 0; r < 5; ++r)
#pragma unroll
    for (int cx = 0; cx < 5; ++cx) win[r][cx] = Ls[ys0 + r][x + 2 + cx];

  for (int yy = 0; yy < 16; ++yy) {
    float s = bv;
#pragma unroll
    for (int ky = 0; ky < 5; ++ky)
#pragma unroll
      for (int kx = 0; kx < 5; ++kx) s = fmaf(win[ky][kx], wreg[ky * 5 + kx], s);
    oplane[(ys0 + yy) * 64 + x] = s;
    if (yy < 15) {
#pragma unroll
      for (int r = 0; r < 4; ++r)
#pragma unroll
        for (int cx = 0; cx < 5; ++cx) win[r][cx] = win[r + 1][cx];
#pragma unroll
      for (int cx = 0; cx < 5; ++cx) win[4][cx] = Ls[ys0 + yy + 5][x + 2 + cx];
    }
  }
}

// --------------------------------------------------------------------------
// 7) final: out[n][dd] = sum_c (xc[c][n] + q3[n][c]) * Wp[dd][c] + bp[dd].
//    Raw barriers (lgkm-only) so t+1 register loads span the sync points.
// --------------------------------------------------------------------------
__global__ __launch_bounds__(256) void final_mfma(
    const half_t* __restrict__ qh, const half_t* __restrict__ ql,
    const float* __restrict__ xc, const float* __restrict__ Wp,
    const float* __restrict__ bp, float* __restrict__ outp) {
  const int b = blockIdx.z, n0 = blockIdx.x * 128, dd0 = blockIdx.y * 128;
  const int tid = threadIdx.x;
  __shared__ __align__(16) half_t As_h[4096], As_l[4096], Bs_h[4096], Bs_l[4096];
  __shared__ __align__(16) float Xs[32 * 130];
  f32x4 acc[4][4] = {};
  const int lane = tid & 63, wave = tid >> 6, wm = wave >> 1, wn = wave & 1;
  const int lr = lane & 15, lg = lane >> 4;

  float4 rxs[4], rwp[4];
  half8 rqh[2][2], rql[2][2];

  auto load_xw = [&](int ks) {
    const int k0 = ks * 32;
#pragma unroll
    for (int r = 0; r < 4; ++r) {
      const int f = tid + r * 256;
      rxs[r] = *(const float4*)&xc[((size_t)b * 256 + k0 + (f >> 5)) * 4096 + n0 + (f & 31) * 4];
      rwp[r] = *(const float4*)&Wp[(size_t)(dd0 + (f >> 3)) * 256 + k0 + (f & 7) * 4];
    }
  };

  load_xw(0);
#pragma unroll
  for (int r = 0; r < 2; ++r) {
    const int f = tid + r * 256;
    const size_t qoff = ((size_t)b * 4096 + n0 + (f >> 2)) * 256 + (f & 3) * 8;
    rqh[0][r] = *(const half8*)&qh[qoff];
    rql[0][r] = *(const half8*)&ql[qoff];
  }

#pragma unroll
  for (int t = 0; t < 8; ++t) {
#pragma unroll
    for (int r = 0; r < 4; ++r) {
      const int f = tid + r * 256;
      const int cc = f >> 5, n4 = f & 31;
      *(float2*)&Xs[cc * 130 + n4 * 4] = make_float2(rxs[r].x, rxs[r].y);
      *(float2*)&Xs[cc * 130 + n4 * 4 + 2] = make_float2(rxs[r].z, rxs[r].w);
      half4 h, l;
      split4(rwp[r], h, l);
      *(half4*)&Bs_h[(f >> 3) * 32 + (f & 7) * 4] = h;
      *(half4*)&Bs_l[(f >> 3) * 32 + (f & 7) * 4] = l;
    }
    WAIT_LGKM0();
    SBAR();
#pragma unroll
    for (int r = 0; r < 2; ++r) {
      const int f = tid + r * 256, row = f >> 2, ch = f & 3;
      const half8 h8 = rqh[t & 1][r];
      const half8 l8 = rql[t & 1][r];
      half8 oh, ol;
#pragma unroll
      for (int u = 0; u < 8; ++u) {
        const float v = (float)h8[u] + (float)l8[u] + Xs[(ch * 8 + u) * 130 + row];
        const half_t h = (half_t)v;
        oh[u] = h;
        ol[u] = (half_t)(v - (float)h);
      }
      *(half8*)&As_h[row * 32 + ch * 8] = oh;
      *(half8*)&As_l[row * 32 + ch * 8] = ol;
    }
    WAIT_LGKM0();
    SBAR();
    if (t + 1 < 8) {
      load_xw(t + 1);
      const int k0n = (t + 1) * 32;
#pragma unroll
      for (int r = 0; r < 2; ++r) {
        const int f = tid + r * 256;
        const size_t qoff = ((size_t)b * 4096 + n0 + (f >> 2)) * 256 + k0n + (f & 3) * 8;
        rqh[(t + 1) & 1][r] = *(const half8*)&qh[qoff];
        rql[(t + 1) & 1][r] = *(const half8*)&ql[qoff];
      }
    }
    frag_compute(As_h, As_l, Bs_h, Bs_l, acc, lane, wm, wn);
    WAIT_LGKM0();
    SBAR();
  }

#pragma unroll
  for (int j = 0; j < 4; ++j) {
    const int dd = dd0 + wn * 64 + j * 16 + lr;
    const float bb = bp[dd];
#pragma unroll
    for (int i = 0; i < 4; ++i) {
      const size_t rowg = (size_t)b * 4096 + n0 + wm * 64 + i * 16 + lg * 4;
#pragma unroll
      for (int r = 0; r < 4; ++r) outp[(rowg + r) * 256 + dd] = acc[i][j][r] + bb;
    }
  }
}

// --------------------------------------------------------------------------
extern "C" void kernel_launch(void* const* d_in, const int* in_sizes, int n_in,
                              void* d_out, int out_size, void* d_ws, size_t ws_size,
                              hipStream_t stream) {
  const float* query = (const float*)d_in[0];
  const float* key   = (const float*)d_in[1];
  const float* value = (const float*)d_in[2];
  const float* Wq    = (const float*)d_in[3];
  const float* Wk    = (const float*)d_in[4];
  const float* Wv    = (const float*)d_in[5];
  const float* Wproj = (const float*)d_in[6];
  const float* bproj = (const float*)d_in[7];
  const float* dwc_w = (const float*)d_in[8];
  const float* dwc_b = (const float*)d_in[9];
  const float* scale = (const float*)d_in[10];

  // Workspace layout. U = 8*4096*256 elems. Peak ~121.8 MB (as R3-R6, ok).
  const size_t U = (size_t)8 * 4096 * 256;
  half_t* qh  = (half_t*)d_ws;            // U halfs, [b][n][c]
  half_t* ql  = qh + U;
  half_t* khT = ql + U;                   // [b][c][m] transposed
  half_t* klT = khT + U;
  half_t* vhT = klT + U;                  // [b][d][m] transposed
  half_t* vlT = vhT + U;
  float*  kvp = (float*)(vlT + U);        // 8*8*65536 fp32 partials
  half_t* kvTh = (half_t*)(kvp + (size_t)8 * 8 * 65536);  // [b][d][c]
  half_t* kvTl = kvTh + (size_t)8 * 65536;
  float*  ksm = (float*)(kvTl + (size_t)8 * 65536);       // [b][256]
  float*  zbuf = ksm + 8 * 256;                            // (unused, kept)
  float*  scs  = zbuf + 32768;                             // [256] 1/softplus
  // aliases (reuse dead regions):
  float* xt = (float*)khT;  // x^T fp32 [b][d][n]  (khT/klT dead after kv)
  float* xc = (float*)vhT;  // conv out [b][c][n]  (vhT/vlT dead after kv)
  float* outp = (float*)d_out;

  const dim3 blk(256);
  init_k<<<dim3(8), blk, 0, stream>>>(scale, scs, ksm);
  proj_mfma<<<dim3(256, 2, 3), blk, 0, stream>>>(query, key, value, Wq, Wk, Wv, scs,
                                                 qh, ql, khT, klT, vhT, vlT, ksm);
  kv_mfma<<<dim3(2, 2, 64), blk, 0, stream>>>(vhT, vlT, khT, klT, kvp);
  kv_red<<<dim3(2048), blk, 0, stream>>>(kvp, kvTh, kvTl);
  x1_mfma<<<dim3(32, 2, 8), blk, 0, stream>>>(qh, ql, kvTh, kvTl, ksm, xt);
  dwconv_kernel<<<dim3(2048), blk, 0, stream>>>(xt, dwc_w, dwc_b, xc);
  final_mfma<<<dim3(32, 2, 8), blk, 0, stream>>>(qh, ql, xc, Wproj, bproj, outp);
}

// Round 8
// 305.962 us; speedup vs baseline: 1.5046x; 1.5046x over previous
//
#include <hip/hip_runtime.h>
#include <math.h>
#include <stdint.h>

// B=8, N=M=4096, C=256, H=W=64, KS=5 (fixed by reference).
#define EPSF 1e-6f

typedef _Float16 half_t;
typedef _Float16 half8 __attribute__((ext_vector_type(8)));
typedef _Float16 half4 __attribute__((ext_vector_type(4)));
typedef float f32x4 __attribute__((ext_vector_type(4)));

#define MFMA16(A, B, C) __builtin_amdgcn_mfma_f32_16x16x32_f16(A, B, C, 0, 0, 0)

#define SBAR() __builtin_amdgcn_s_barrier()
#define WAIT_LGKM0()                                        \
  do {                                                      \
    asm volatile("s_waitcnt lgkmcnt(0)" ::: "memory");      \
    __builtin_amdgcn_sched_barrier(0);                      \
  } while (0)
#define WAIT_VM0_LGKM0()                                            \
  do {                                                              \
    asm volatile("s_waitcnt vmcnt(0) lgkmcnt(0)" ::: "memory");     \
    __builtin_amdgcn_sched_barrier(0);                              \
  } while (0)

__device__ __forceinline__ float softplusf(float x) {
  return (x > 20.f) ? x : log1pf(expf(x));
}

__device__ __forceinline__ void split4(const float4 v, half4& h, half4& l) {
  h.x = (half_t)v.x; l.x = (half_t)(v.x - (float)h.x);
  h.y = (half_t)v.y; l.y = (half_t)(v.y - (float)h.y);
  h.z = (half_t)v.z; l.z = (half_t)(v.z - (float)h.z);
  h.w = (half_t)v.w; l.w = (half_t)(v.w - (float)h.w);
}

// --------------------------------------------------------------------------
// Shared MFMA machinery: 128x128 tile, BK=32, 256 threads (4 waves 2x2),
// wave tile 64x64 = 4x4 frags of 16x16x32 f16 MFMA, 3-term hi/lo split.
// SINGLE 32 KB LDS buffer (4 planes x 8 KB). NO min-waves launch_bounds:
// R7 showed forcing 4 waves/EU caps VGPR at 64 -> acc spills to scratch
// (FETCH 52->256MB, WRITE 98->455MB). Let the allocator take ~128 VGPR;
// VGPR then limits to 16 waves/CU = 4 blocks/CU, no spills.
// --------------------------------------------------------------------------

__device__ __forceinline__ void stage_gld(const half_t* __restrict__ src, size_t rowbase,
                                          int ld, int k0, half_t* __restrict__ dst, int tid) {
#pragma unroll
  for (int r = 0; r < 2; ++r) {
    const int f = tid + r * 256;          // 128 rows x 4 chunks of 8 halfs
    const half_t* g = src + (rowbase + (size_t)(f >> 2)) * (size_t)ld + k0 + (f & 3) * 8;
    const __attribute__((address_space(1))) unsigned int* gp =
        (const __attribute__((address_space(1))) unsigned int*)(uintptr_t)g;
    __attribute__((address_space(3))) unsigned int* lp =
        (__attribute__((address_space(3))) unsigned int*)(uintptr_t)(dst + f * 8);
    __builtin_amdgcn_global_load_lds(gp, lp, 16, 0, 0);
  }
}

__device__ __forceinline__ void frag_compute(const half_t* __restrict__ As_h,
                                             const half_t* __restrict__ As_l,
                                             const half_t* __restrict__ Bs_h,
                                             const half_t* __restrict__ Bs_l,
                                             f32x4 (&acc)[4][4], int lane, int wm, int wn) {
  const int lr = lane & 15, lg = lane >> 4;
  half8 ah[4], al[4], bh[4], bl[4];
#pragma unroll
  for (int i = 0; i < 4; ++i) {
    const int ar = (wm * 64 + i * 16 + lr) * 32 + lg * 8;
    ah[i] = *(const half8*)&As_h[ar];
    al[i] = *(const half8*)&As_l[ar];
    const int br = (wn * 64 + i * 16 + lr) * 32 + lg * 8;
    bh[i] = *(const half8*)&Bs_h[br];
    bl[i] = *(const half8*)&Bs_l[br];
  }
#pragma unroll
  for (int i = 0; i < 4; ++i)
#pragma unroll
    for (int j = 0; j < 4; ++j) {
      acc[i][j] = MFMA16(ah[i], bh[j], acc[i][j]);
      acc[i][j] = MFMA16(ah[i], bl[j], acc[i][j]);
      acc[i][j] = MFMA16(al[i], bh[j], acc[i][j]);
    }
}

// --------------------------------------------------------------------------
// 0) init: scs[c] = 1/softplus(scale[c]); zero ksm (proj atomicAdds into it).
// --------------------------------------------------------------------------
__global__ void init_k(const float* __restrict__ scale, float* __restrict__ scs,
                       float* __restrict__ ksm) {
  const int i = blockIdx.x * 256 + threadIdx.x;
  if (i < 2048) ksm[i] = 0.f;
  if (i < 256) scs[i] = 1.f / softplusf(scale[i]);
}

// --------------------------------------------------------------------------
// 1) Projections: single-buffer 32 KB, 2 barriers/step; t+1 reg loads issued
//    before compute(t) so they hide under the MFMA phase.
//    which==0 (q): A=Wq, B=query -> coalesced half4 stores along d.
//    which==1/2 (k/v): transposed [b][c][m] out via chunked LDS restage.
//    which==1 additionally atomicAdds ksum partials into ksm.
// --------------------------------------------------------------------------
__global__ __launch_bounds__(256) void proj_mfma(
    const float* __restrict__ query, const float* __restrict__ key,
    const float* __restrict__ value,
    const float* __restrict__ Wq, const float* __restrict__ Wk, const float* __restrict__ Wv,
    const float* __restrict__ rsc,
    half_t* __restrict__ qh, half_t* __restrict__ ql,
    half_t* __restrict__ khT, half_t* __restrict__ klT,
    half_t* __restrict__ vhT, half_t* __restrict__ vlT,
    float* __restrict__ ksm) {
  const int which = blockIdx.z;
  const int tid = threadIdx.x;
  const int lane = tid & 63, wave = tid >> 6, wm = wave >> 1, wn = wave & 1;
  const int lr = lane & 15, lg = lane >> 4;

  const float* srcA;
  const float* srcB;
  int rA0, rB0;
  if (which == 0) {
    srcA = Wq;    rA0 = blockIdx.y * 128;  srcB = query; rB0 = blockIdx.x * 128;
  } else if (which == 1) {
    srcA = key;   rA0 = blockIdx.x * 128;  srcB = Wk;    rB0 = blockIdx.y * 128;
  } else {
    srcA = value; rA0 = blockIdx.x * 128;  srcB = Wv;    rB0 = blockIdx.y * 128;
  }

  __shared__ __align__(16) half_t sm[16384];  // {Ah,Al,Bh,Bl} x 4096 halfs
  f32x4 acc[4][4] = {};
  float4 RA[4], RB[4];

  auto load_tile = [&](int ks) {
    const int k0 = ks * 32;
#pragma unroll
    for (int r = 0; r < 4; ++r) {
      const int f = tid + r * 256;
      const int row = f >> 3, c4 = f & 7;
      RA[r] = *(const float4*)&srcA[(size_t)(rA0 + row) * 256 + k0 + c4 * 4];
      RB[r] = *(const float4*)&srcB[(size_t)(rB0 + row) * 256 + k0 + c4 * 4];
    }
  };
  auto split_write = [&]() {
#pragma unroll
    for (int r = 0; r < 4; ++r) {
      const int f = tid + r * 256;
      const int row = f >> 3, c4 = f & 7;
      half4 h, l;
      split4(RA[r], h, l);
      *(half4*)&sm[row * 32 + c4 * 4] = h;
      *(half4*)&sm[4096 + row * 32 + c4 * 4] = l;
      split4(RB[r], h, l);
      *(half4*)&sm[8192 + row * 32 + c4 * 4] = h;
      *(half4*)&sm[12288 + row * 32 + c4 * 4] = l;
    }
  };

  load_tile(0);
  split_write();
  WAIT_LGKM0();
  SBAR();
#pragma unroll
  for (int t = 0; t < 8; ++t) {
    if (t + 1 < 8) load_tile(t + 1);  // async reg loads, consumed after next bar
    frag_compute(sm, sm + 4096, sm + 8192, sm + 12288, acc, lane, wm, wn);
    SBAR();  // all waves done reading sm
    if (t + 1 < 8) {
      split_write();
      WAIT_LGKM0();
    }
    SBAR();  // writes visible
  }

  if (which == 0) {
    // D: row = d_local (A=Wq side), col = n_local. Store along d (contiguous).
    const int dbase = rA0 + wm * 64;
    float rs[4][4];
#pragma unroll
    for (int i = 0; i < 4; ++i)
#pragma unroll
      for (int r = 0; r < 4; ++r) rs[i][r] = rsc[dbase + i * 16 + lg * 4 + r];
#pragma unroll
    for (int j = 0; j < 4; ++j) {
      const size_t nflat = (size_t)rB0 + wn * 64 + j * 16 + lr;
#pragma unroll
      for (int i = 0; i < 4; ++i) {
        half4 hv, lv;
#pragma unroll
        for (int r = 0; r < 4; ++r) {
          float v = acc[i][j][r];
          v = (fmaxf(v, 0.f) + EPSF) * rs[i][r];
          v = v * v * v;  // q**3/||q||*||q|| == q**3
          const half_t h = (half_t)v;
          hv[r] = h;
          lv[r] = (half_t)(v - (float)h);
        }
        const size_t o = nflat * 256 + dbase + i * 16 + lg * 4;
        *(half4*)&qh[o] = hv;
        *(half4*)&ql[o] = lv;
      }
    }
  } else {
    // D: row = m_local, col = c_local. Restage [32 c][128 m] chunks in LDS,
    // then coalesced half8 stores. which==1: accumulate ksum partials too.
    const int b = rA0 >> 12, m0 = rA0 & 4095;
    half_t* Thg = (which == 1) ? khT : vhT;
    half_t* Tlg = (which == 1) ? klT : vlT;
    const bool act = (which == 1);
    half_t* Tt = sm;            // [32][136]
    half_t* Tl2 = sm + 4352;    // [32][136]
    float kj[4] = {0.f, 0.f, 0.f, 0.f};
#pragma unroll
    for (int g = 0; g < 4; ++g) {
      if (wn == (g >> 1)) {
#pragma unroll
        for (int jj = 0; jj < 2; ++jj) {
          const int j = (g & 1) * 2 + jj;
          const int c = rB0 + wn * 64 + j * 16 + lr;
          const float rv = act ? rsc[c] : 1.f;
          const int crel = jj * 16 + lr;
#pragma unroll
          for (int i = 0; i < 4; ++i) {
            const int ml = wm * 64 + i * 16 + lg * 4;
            half4 hv, lv;
#pragma unroll
            for (int r = 0; r < 4; ++r) {
              float v = acc[i][j][r];
              if (act) { v = (fmaxf(v, 0.f) + EPSF) * rv; v = v * v * v; kj[j] += v; }
              const half_t h = (half_t)v;
              hv[r] = h;
              lv[r] = (half_t)(v - (float)h);
            }
            *(half4*)&Tt[crel * 136 + ml] = hv;
            *(half4*)&Tl2[crel * 136 + ml] = lv;
          }
        }
      }
      __syncthreads();
      {
        const int cr = tid >> 3, mm = (tid & 7) * 16;
        const size_t ga = ((size_t)(b * 256 + rB0 + g * 32 + cr)) * 4096 + m0 + mm;
        *(half8*)&Thg[ga]     = *(const half8*)&Tt[cr * 136 + mm];
        *(half8*)&Thg[ga + 8] = *(const half8*)&Tt[cr * 136 + mm + 8];
        *(half8*)&Tlg[ga]     = *(const half8*)&Tl2[cr * 136 + mm];
        *(half8*)&Tlg[ga + 8] = *(const half8*)&Tl2[cr * 136 + mm + 8];
      }
      __syncthreads();
    }
    if (act) {
#pragma unroll
      for (int j = 0; j < 4; ++j) {
        float s = kj[j];
        s += __shfl_xor(s, 16, 64);
        s += __shfl_xor(s, 32, 64);
        if (lg == 0) atomicAdd(&ksm[b * 256 + rB0 + wn * 64 + j * 16 + lr], s);
      }
    }
  }
}

// --------------------------------------------------------------------------
// 3) kv partials: kvT[d][c] = sum_m v[m][d]*k3[m][c]. Single-buffer m97
//    schedule: stage -> drain -> bar -> compute -> bar. 32 KB LDS.
// --------------------------------------------------------------------------
__global__ __launch_bounds__(256) void kv_mfma(
    const half_t* __restrict__ vhT, const half_t* __restrict__ vlT,
    const half_t* __restrict__ khT, const half_t* __restrict__ klT,
    float* __restrict__ kvp) {
  const int b = blockIdx.z >> 3, s = blockIdx.z & 7;
  const int d0 = blockIdx.x * 128, c0 = blockIdx.y * 128;
  const int tid = threadIdx.x;
  __shared__ __align__(16) half_t sm[16384];
  f32x4 acc[4][4] = {};
  const int lane = tid & 63, wave = tid >> 6, wm = wave >> 1, wn = wave & 1;
  const int lr = lane & 15, lg = lane >> 4;
  const size_t arow = (size_t)b * 256 + d0, brow = (size_t)b * 256 + c0;

#pragma unroll
  for (int t = 0; t < 16; ++t) {
    const int k0 = s * 512 + t * 32;
    stage_gld(vhT, arow, 4096, k0, sm, tid);
    stage_gld(vlT, arow, 4096, k0, sm + 4096, tid);
    stage_gld(khT, brow, 4096, k0, sm + 8192, tid);
    stage_gld(klT, brow, 4096, k0, sm + 12288, tid);
    WAIT_VM0_LGKM0();
    SBAR();
    frag_compute(sm, sm + 4096, sm + 8192, sm + 12288, acc, lane, wm, wn);
    SBAR();
  }

  float* outp = kvp + ((size_t)(b * 8 + s)) * 65536;
#pragma unroll
  for (int j = 0; j < 4; ++j) {
    const int c = c0 + wn * 64 + j * 16 + lr;
#pragma unroll
    for (int i = 0; i < 4; ++i) {
      const int d = d0 + wm * 64 + i * 16 + lg * 4;
#pragma unroll
      for (int r = 0; r < 4; ++r) outp[(size_t)(d + r) * 256 + c] = acc[i][j][r];
    }
  }
}

__global__ __launch_bounds__(256) void kv_red(const float* __restrict__ kvp,
                                              half_t* __restrict__ kvTh,
                                              half_t* __restrict__ kvTl) {
  const size_t idx = (size_t)blockIdx.x * 256 + threadIdx.x;  // 524288
  const int b = (int)(idx >> 16);
  const int dc = (int)(idx & 65535);
  float s = 0.f;
#pragma unroll
  for (int t = 0; t < 8; ++t) s += kvp[((size_t)(b * 8 + t)) * 65536 + dc];
  const half_t h = (half_t)s;
  kvTh[idx] = h;
  kvTl[idx] = (half_t)(s - (float)h);
}

// --------------------------------------------------------------------------
// 5) x1[n][d] = (q3[n,:].kvT[d,:]) * z[n], z fused in-kernel from staged q
//    planes. Single-buffer m97 schedule, 32 KB LDS. Out: xt[b][d][n] fp32.
// --------------------------------------------------------------------------
__global__ __launch_bounds__(256) void x1_mfma(
    const half_t* __restrict__ qh, const half_t* __restrict__ ql,
    const half_t* __restrict__ kvTh, const half_t* __restrict__ kvTl,
    const float* __restrict__ ksm, float* __restrict__ xt) {
  const int b = blockIdx.z, n0 = blockIdx.x * 128, d0t = blockIdx.y * 128;
  const int tid = threadIdx.x;
  __shared__ __align__(16) half_t sm[16384];
  __shared__ float zden[128];
  f32x4 acc[4][4] = {};
  const int lane = tid & 63, wave = tid >> 6, wm = wave >> 1, wn = wave & 1;
  const int lr = lane & 15, lg = lane >> 4;
  const size_t arow = (size_t)b * 4096 + n0, brow = (size_t)b * 256 + d0t;

  float zpart = 0.f;
  const int zrow = tid >> 1, zkh = tid & 1;
#pragma unroll
  for (int t = 0; t < 8; ++t) {
    const int k0 = t * 32;
    stage_gld(qh, arow, 256, k0, sm, tid);
    stage_gld(ql, arow, 256, k0, sm + 4096, tid);
    stage_gld(kvTh, brow, 256, k0, sm + 8192, tid);
    stage_gld(kvTl, brow, 256, k0, sm + 12288, tid);
    WAIT_VM0_LGKM0();
    SBAR();
    frag_compute(sm, sm + 4096, sm + 8192, sm + 12288, acc, lane, wm, wn);
    {  // z partial: q3 row dot ksum for this k-chunk (reads staged planes)
      const half_t* hp = sm + zrow * 32 + zkh * 16;
      const half_t* lp = sm + 4096 + zrow * 32 + zkh * 16;
      const half8 h0 = *(const half8*)&hp[0];
      const half8 h1 = *(const half8*)&hp[8];
      const half8 l0 = *(const half8*)&lp[0];
      const half8 l1 = *(const half8*)&lp[8];
      const float* ksp = ksm + b * 256 + t * 32 + zkh * 16;
#pragma unroll
      for (int u = 0; u < 8; ++u) {
        zpart += ((float)h0[u] + (float)l0[u]) * ksp[u];
        zpart += ((float)h1[u] + (float)l1[u]) * ksp[8 + u];
      }
    }
    SBAR();
  }

  zpart += __shfl_xor(zpart, 1, 64);
  if ((tid & 1) == 0) zden[zrow] = zpart;
  __syncthreads();

#pragma unroll
  for (int i = 0; i < 4; ++i) {
    const int nl = wm * 64 + i * 16 + lg * 4;  // local row in [0,128)
    float zr[4];
#pragma unroll
    for (int r = 0; r < 4; ++r) zr[r] = 1.f / (zden[nl + r] + EPSF);
#pragma unroll
    for (int j = 0; j < 4; ++j) {
      const int d = d0t + wn * 64 + j * 16 + lr;
      *(float4*)&xt[((size_t)b * 256 + d) * 4096 + n0 + nl] =
          make_float4(acc[i][j][0] * zr[0], acc[i][j][1] * zr[1],
                      acc[i][j][2] * zr[2], acc[i][j][3] * zr[3]);
    }
  }
}

// --------------------------------------------------------------------------
// 6) Depthwise 5x5 conv + bias on (B,C,64,64) planes (verified).
// --------------------------------------------------------------------------
__global__ __launch_bounds__(256) void dwconv_kernel(const float* __restrict__ xt,
                                                     const float* __restrict__ w,
                                                     const float* __restrict__ bias,
                                                     float* __restrict__ xc) {
  const int bc = blockIdx.x;  // b*256 + c
  const int c = bc & 255;
  const float* plane = xt + (size_t)bc * 4096;
  float* oplane = xc + (size_t)bc * 4096;

  __shared__ float Ls[68][72];
  const int tid = threadIdx.x;
  for (int i = tid; i < 68 * 72; i += 256) ((float*)Ls)[i] = 0.f;
  __syncthreads();
#pragma unroll
  for (int p = 0; p < 4; ++p) {
    const int f = tid + p * 256;
    const int y = f >> 4, x4 = f & 15;
    *(float4*)&Ls[2 + y][4 + x4 * 4] = *(const float4*)&plane[y * 64 + x4 * 4];
  }
  __syncthreads();

  float wreg[25];
#pragma unroll
  for (int t = 0; t < 25; ++t) wreg[t] = w[c * 25 + t];
  const float bv = bias[c];

  const int x = tid & 63, ys0 = (tid >> 6) * 16;
  float win[5][5];
#pragma unroll
  for (int r = 0; r < 5; ++r)
#pragma unroll
    for (int cx = 0; cx < 5; ++cx) win[r][cx] = Ls[ys0 + r][x + 2 + cx];

  for (int yy = 0; yy < 16; ++yy) {
    float s = bv;
#pragma unroll
    for (int ky = 0; ky < 5; ++ky)
#pragma unroll
      for (int kx = 0; kx < 5; ++kx) s = fmaf(win[ky][kx], wreg[ky * 5 + kx], s);
    oplane[(ys0 + yy) * 64 + x] = s;
    if (yy < 15) {
#pragma unroll
      for (int r = 0; r < 4; ++r)
#pragma unroll
        for (int cx = 0; cx < 5; ++cx) win[r][cx] = win[r + 1][cx];
#pragma unroll
      for (int cx = 0; cx < 5; ++cx) win[4][cx] = Ls[ys0 + yy + 5][x + 2 + cx];
    }
  }
}

// --------------------------------------------------------------------------
// 7) final: out[n][dd] = sum_c (xc[c][n] + q3[n][c]) * Wp[dd][c] + bp[dd].
//    Raw barriers (lgkm-only) so t+1 register loads span the sync points.
// --------------------------------------------------------------------------
__global__ __launch_bounds__(256) void final_mfma(
    const half_t* __restrict__ qh, const half_t* __restrict__ ql,
    const float* __restrict__ xc, const float* __restrict__ Wp,
    const float* __restrict__ bp, float* __restrict__ outp) {
  const int b = blockIdx.z, n0 = blockIdx.x * 128, dd0 = blockIdx.y * 128;
  const int tid = threadIdx.x;
  __shared__ __align__(16) half_t As_h[4096], As_l[4096], Bs_h[4096], Bs_l[4096];
  __shared__ __align__(16) float Xs[32 * 130];
  f32x4 acc[4][4] = {};
  const int lane = tid & 63, wave = tid >> 6, wm = wave >> 1, wn = wave & 1;
  const int lr = lane & 15, lg = lane >> 4;

  float4 rxs[4], rwp[4];
  half8 rqh[2][2], rql[2][2];

  auto load_xw = [&](int ks) {
    const int k0 = ks * 32;
#pragma unroll
    for (int r = 0; r < 4; ++r) {
      const int f = tid + r * 256;
      rxs[r] = *(const float4*)&xc[((size_t)b * 256 + k0 + (f >> 5)) * 4096 + n0 + (f & 31) * 4];
      rwp[r] = *(const float4*)&Wp[(size_t)(dd0 + (f >> 3)) * 256 + k0 + (f & 7) * 4];
    }
  };

  load_xw(0);
#pragma unroll
  for (int r = 0; r < 2; ++r) {
    const int f = tid + r * 256;
    const size_t qoff = ((size_t)b * 4096 + n0 + (f >> 2)) * 256 + (f & 3) * 8;
    rqh[0][r] = *(const half8*)&qh[qoff];
    rql[0][r] = *(const half8*)&ql[qoff];
  }

#pragma unroll
  for (int t = 0; t < 8; ++t) {
#pragma unroll
    for (int r = 0; r < 4; ++r) {
      const int f = tid + r * 256;
      const int cc = f >> 5, n4 = f & 31;
      *(float2*)&Xs[cc * 130 + n4 * 4] = make_float2(rxs[r].x, rxs[r].y);
      *(float2*)&Xs[cc * 130 + n4 * 4 + 2] = make_float2(rxs[r].z, rxs[r].w);
      half4 h, l;
      split4(rwp[r], h, l);
      *(half4*)&Bs_h[(f >> 3) * 32 + (f & 7) * 4] = h;
      *(half4*)&Bs_l[(f >> 3) * 32 + (f & 7) * 4] = l;
    }
    WAIT_LGKM0();
    SBAR();
#pragma unroll
    for (int r = 0; r < 2; ++r) {
      const int f = tid + r * 256, row = f >> 2, ch = f & 3;
      const half8 h8 = rqh[t & 1][r];
      const half8 l8 = rql[t & 1][r];
      half8 oh, ol;
#pragma unroll
      for (int u = 0; u < 8; ++u) {
        const float v = (float)h8[u] + (float)l8[u] + Xs[(ch * 8 + u) * 130 + row];
        const half_t h = (half_t)v;
        oh[u] = h;
        ol[u] = (half_t)(v - (float)h);
      }
      *(half8*)&As_h[row * 32 + ch * 8] = oh;
      *(half8*)&As_l[row * 32 + ch * 8] = ol;
    }
    WAIT_LGKM0();
    SBAR();
    if (t + 1 < 8) {
      load_xw(t + 1);
      const int k0n = (t + 1) * 32;
#pragma unroll
      for (int r = 0; r < 2; ++r) {
        const int f = tid + r * 256;
        const size_t qoff = ((size_t)b * 4096 + n0 + (f >> 2)) * 256 + k0n + (f & 3) * 8;
        rqh[(t + 1) & 1][r] = *(const half8*)&qh[qoff];
        rql[(t + 1) & 1][r] = *(const half8*)&ql[qoff];
      }
    }
    frag_compute(As_h, As_l, Bs_h, Bs_l, acc, lane, wm, wn);
    WAIT_LGKM0();
    SBAR();
  }

#pragma unroll
  for (int j = 0; j < 4; ++j) {
    const int dd = dd0 + wn * 64 + j * 16 + lr;
    const float bb = bp[dd];
#pragma unroll
    for (int i = 0; i < 4; ++i) {
      const size_t rowg = (size_t)b * 4096 + n0 + wm * 64 + i * 16 + lg * 4;
#pragma unroll
      for (int r = 0; r < 4; ++r) outp[(rowg + r) * 256 + dd] = acc[i][j][r] + bb;
    }
  }
}

// --------------------------------------------------------------------------
extern "C" void kernel_launch(void* const* d_in, const int* in_sizes, int n_in,
                              void* d_out, int out_size, void* d_ws, size_t ws_size,
                              hipStream_t stream) {
  const float* query = (const float*)d_in[0];
  const float* key   = (const float*)d_in[1];
  const float* value = (const float*)d_in[2];
  const float* Wq    = (const float*)d_in[3];
  const float* Wk    = (const float*)d_in[4];
  const float* Wv    = (const float*)d_in[5];
  const float* Wproj = (const float*)d_in[6];
  const float* bproj = (const float*)d_in[7];
  const float* dwc_w = (const float*)d_in[8];
  const float* dwc_b = (const float*)d_in[9];
  const float* scale = (const float*)d_in[10];

  // Workspace layout. U = 8*4096*256 elems. Peak ~121.8 MB (as R3-R6, ok).
  const size_t U = (size_t)8 * 4096 * 256;
  half_t* qh  = (half_t*)d_ws;            // U halfs, [b][n][c]
  half_t* ql  = qh + U;
  half_t* khT = ql + U;                   // [b][c][m] transposed
  half_t* klT = khT + U;
  half_t* vhT = klT + U;                  // [b][d][m] transposed
  half_t* vlT = vhT + U;
  float*  kvp = (float*)(vlT + U);        // 8*8*65536 fp32 partials
  half_t* kvTh = (half_t*)(kvp + (size_t)8 * 8 * 65536);  // [b][d][c]
  half_t* kvTl = kvTh + (size_t)8 * 65536;
  float*  ksm = (float*)(kvTl + (size_t)8 * 65536);       // [b][256]
  float*  zbuf = ksm + 8 * 256;                            // (unused, kept)
  float*  scs  = zbuf + 32768;                             // [256] 1/softplus
  // aliases (reuse dead regions):
  float* xt = (float*)khT;  // x^T fp32 [b][d][n]  (khT/klT dead after kv)
  float* xc = (float*)vhT;  // conv out [b][c][n]  (vhT/vlT dead after kv)
  float* outp = (float*)d_out;

  const dim3 blk(256);
  init_k<<<dim3(8), blk, 0, stream>>>(scale, scs, ksm);
  proj_mfma<<<dim3(256, 2, 3), blk, 0, stream>>>(query, key, value, Wq, Wk, Wv, scs,
                                                 qh, ql, khT, klT, vhT, vlT, ksm);
  kv_mfma<<<dim3(2, 2, 64), blk, 0, stream>>>(vhT, vlT, khT, klT, kvp);
  kv_red<<<dim3(2048), blk, 0, stream>>>(kvp, kvTh, kvTl);
  x1_mfma<<<dim3(32, 2, 8), blk, 0, stream>>>(qh, ql, kvTh, kvTl, ksm, xt);
  dwconv_kernel<<<dim3(2048), blk, 0, stream>>>(xt, dwc_w, dwc_b, xc);
  final_mfma<<<dim3(32, 2, 8), blk, 0, stream>>>(qh, ql, xc, Wproj, bproj, outp);
}